// Round 8
// baseline (187.811 us; speedup 1.0000x reference)
//
#include <hip/hip_runtime.h>

#define NB 8
#define NN 256
#define NS 128
#define NM 8192
#define NK 200
#define KP1 201
#define FEPS 1e-9f
#define GROUP_BLOCKS (NB * NN)   // 2048
#define CD1B_BLOCKS 256
#define HBINS 2048

// ---------- reduction helpers (256 threads = 4 waves) ----------
__device__ __forceinline__ float block_sum_f(float v, float* redf) {
    const int tid = threadIdx.x, w = tid >> 6, l = tid & 63;
    for (int o = 32; o; o >>= 1) v += __shfl_xor(v, o);
    if (l == 0) redf[w] = v;
    __syncthreads();
    float t = redf[0] + redf[1] + redf[2] + redf[3];
    __syncthreads();
    return t;
}

// exclusive prefix over 256 threads; also returns block total
__device__ __forceinline__ int block_excl_scan_i(int v, int* redi, int tid, int& total) {
    const int l = tid & 63, w = tid >> 6;
    int x = v;
    for (int o = 1; o < 64; o <<= 1) { int y = __shfl_up(x, o); if (l >= o) x += y; }
    if (l == 63) redi[w] = x;
    __syncthreads();
    int woff = 0;
#pragma unroll
    for (int j = 0; j < 4; ++j) { if (j < w) woff += redi[j]; }
    total = redi[0] + redi[1] + redi[2] + redi[3];
    int ex = woff + x - v;
    __syncthreads();
    return ex;
}

// find the bin where the cumulative histogram count reaches rem;
// updates rem to the residual count needed inside that bin.
__device__ __forceinline__ int find_bin(int* hist, int nbins, int& rem,
                                        int* redi, int* ibc, int tid) {
    const int C = nbins >> 8;        // bins per thread (contiguous chunk)
    const int base = tid * C;
    int local = 0;
    for (int j = 0; j < C; ++j) local += hist[base + j];
    int total;
    int ex = block_excl_scan_i(local, redi, tid, total);
    if (ex < rem && rem <= ex + local) {       // exactly one thread
        int run = ex;
        for (int j = 0; j < C; ++j) {
            int h = hist[base + j];
            if (run + h >= rem) { ibc[0] = base + j; ibc[1] = rem - run; break; }
            run += h;
        }
    }
    __syncthreads();
    int bin = ibc[0]; rem = ibc[1];
    __syncthreads();
    return bin;
}

// ---------- single kernel: 2048 group blocks + 256 cd1b blocks ----------
// Each block atomically adds its weighted contribution into out[0..2].
__global__ __launch_bounds__(256)
void k_main(const float* __restrict__ means, const float* __restrict__ sp,
            const float* __restrict__ gt, float* __restrict__ out) {
    __shared__ float gx[NK], gy[NK], gz[NK];
    __shared__ float sx[NS], sy[NS], sz[NS];
    __shared__ int   hist[HBINS];
    __shared__ float redf[4];
    __shared__ int   redi[4];
    __shared__ int   ibc[2];

    const int tid = threadIdx.x;
    const int w = tid >> 6, l = tid & 63;

    if (blockIdx.x >= GROUP_BLOCKS) {
        // ---- cd1 term 2: per (b,m) min over the 256 means ----
        const int blk = blockIdx.x - GROUP_BLOCKS;   // 0..255
        const int b = blk >> 5;
        const int m = ((blk & 31) << 8) + tid;
        float* mxs = (float*)hist;                   // reuse hist LDS (256*3 floats)
        float* mys = mxs + NN;
        float* mzs = mys + NN;
        const float* mb = means + (size_t)b * NN * 3;
        mxs[tid] = mb[tid * 3 + 0];
        mys[tid] = mb[tid * 3 + 1];
        mzs[tid] = mb[tid * 3 + 2];
        __syncthreads();
        const float* gp = gt + ((size_t)b * NM + m) * 3;
        const float px = gp[0], py = gp[1], pz = gp[2];
        float mn = 3.4e38f;
#pragma unroll 8
        for (int n = 0; n < NN; ++n) {
            float dx = px - mxs[n], dy = py - mys[n], dz = pz - mzs[n];
            mn = fminf(mn, fmaf(dx, dx, fmaf(dy, dy, dz * dz)));
        }
        float d2 = sqrtf(fmaxf(mn, FEPS));
        float t4 = block_sum_f(d2, redf);
        if (tid == 0)
            atomicAdd(out + 1, 1000.0f * 0.5f * t4 / ((float)NB * NM));
        return;
    }

    // ---- group path: one block per (b,n) ----
    const int bn = blockIdx.x;
    const int b  = bn >> 8;

    const float* spb = sp + (size_t)bn * NS * 3;
    if (tid < NS) {
        sx[tid] = spb[tid * 3 + 0];
        sy[tid] = spb[tid * 3 + 1];
        sz[tid] = spb[tid * 3 + 2];
    }
    const float mx = means[bn * 3 + 0];
    const float my = means[bn * 3 + 1];
    const float mz = means[bn * 3 + 2];
    const float* g = gt + (size_t)b * NM * 3;

    // 32 distances per thread in registers
    float vd[32];
    float vmin = 3.4e38f; int varg = -1;
#pragma unroll
    for (int i = 0; i < 32; ++i) {
        int m = tid + i * 256;
        float dx = mx - g[m * 3 + 0];
        float dy = my - g[m * 3 + 1];
        float dz = mz - g[m * 3 + 2];
        float d = fmaf(dx, dx, fmaf(dy, dy, dz * dz));
        vd[i] = d;
        if (d < vmin) { vmin = d; varg = m; }
    }

    // block argmin (value,index), lowest index on ties
    for (int o = 32; o; o >>= 1) {
        float ov = __shfl_xor(vmin, o);
        int   oi = __shfl_xor(varg, o);
        if (ov < vmin || (ov == vmin && oi < varg)) { vmin = ov; varg = oi; }
    }
    if (l == 0) { redf[w] = vmin; redi[w] = varg; }
    __syncthreads();
    float dmin = redf[0]; int m0 = redi[0];
#pragma unroll
    for (int i = 1; i < 4; ++i) {
        if (redf[i] < dmin || (redf[i] == dmin && redi[i] < m0)) { dmin = redf[i]; m0 = redi[i]; }
    }
    float cd1a = 0.0f;
    if (tid == 0) cd1a = sqrtf(fmaxf(dmin, FEPS));
    __syncthreads();

    // ---- exact 201st-smallest via 3-level histogram radix (bits 30..20, 19..9, 8..0) ----
    int rem = KP1;
    unsigned prefix;
    for (int j = tid; j < HBINS; j += 256) hist[j] = 0;
    __syncthreads();
#pragma unroll
    for (int i = 0; i < 32; ++i) atomicAdd(&hist[__float_as_uint(vd[i]) >> 20], 1);
    __syncthreads();
    prefix = (unsigned)find_bin(hist, 2048, rem, redi, ibc, tid);
    for (int j = tid; j < HBINS; j += 256) hist[j] = 0;
    __syncthreads();
#pragma unroll
    for (int i = 0; i < 32; ++i) {
        unsigned u = __float_as_uint(vd[i]);
        if ((u >> 20) == prefix) atomicAdd(&hist[(u >> 9) & 2047], 1);
    }
    __syncthreads();
    prefix = (prefix << 11) | (unsigned)find_bin(hist, 2048, rem, redi, ibc, tid);
    for (int j = tid; j < 512; j += 256) hist[j] = 0;
    __syncthreads();
#pragma unroll
    for (int i = 0; i < 32; ++i) {
        unsigned u = __float_as_uint(vd[i]);
        if ((u >> 9) == prefix) atomicAdd(&hist[u & 511], 1);
    }
    __syncthreads();
    const unsigned X = (prefix << 9) | (unsigned)find_bin(hist, 512, rem, redi, ibc, tid);

    // ---- gather selected set: strict-less via scan, ties fill ----
    int c = 0;
#pragma unroll
    for (int i = 0; i < 32; ++i) {
        int m = tid + i * 256;
        c += (m != m0 && __float_as_uint(vd[i]) < X);
    }
    int total;
    int p = block_excl_scan_i(c, redi, tid, total);
#pragma unroll
    for (int i = 0; i < 32; ++i) {
        int m = tid + i * 256;
        if (m != m0 && __float_as_uint(vd[i]) < X) {
            gx[p] = g[m * 3 + 0]; gy[p] = g[m * 3 + 1]; gz[p] = g[m * 3 + 2];
            ++p;
        }
    }
    if (tid == 0) ibc[0] = total;
    __syncthreads();
#pragma unroll
    for (int i = 0; i < 32; ++i) {
        int m = tid + i * 256;
        if (m != m0 && __float_as_uint(vd[i]) == X) {
            int q = atomicAdd(&ibc[0], 1);
            if (q < NK) { gx[q] = g[m * 3 + 0]; gy[q] = g[m * 3 + 1]; gz[q] = g[m * 3 + 2]; }
        }
    }
    __syncthreads();

    // ---- combined chamfer: one evaluation of the 128x200 matrix ----
    // thread (ts, tk) = (tid&15, tid>>4): 8 s-rows in regs x 13 k-cols.
    const int ts = tid & 15, tk = tid >> 4;
    float psx[8], psy[8], psz[8];
#pragma unroll
    for (int j = 0; j < 8; ++j) {
        int s = ts * 8 + j;
        psx[j] = sx[s]; psy[j] = sy[s]; psz[j] = sz[s];
    }
    float rowmin[8];
#pragma unroll
    for (int j = 0; j < 8; ++j) rowmin[j] = 3.4e38f;
    float d2acc = 0.0f;
#pragma unroll
    for (int i = 0; i < 13; ++i) {
        int k = tk + 16 * i;
        if (k < NK) {                       // wave-uniform: only waves 2,3 skip i==12
            float qx = gx[k], qy = gy[k], qz = gz[k];
            float cm = 3.4e38f;
#pragma unroll
            for (int j = 0; j < 8; ++j) {
                float dx = psx[j] - qx, dy = psy[j] - qy, dz = psz[j] - qz;
                float d = fmaf(dx, dx, fmaf(dy, dy, dz * dz));
                rowmin[j] = fminf(rowmin[j], d);
                cm = fminf(cm, d);
            }
            // col-min over the 16 lanes sharing tk (lanes are contiguous 16-groups)
            cm = fminf(cm, __shfl_xor(cm, 1));
            cm = fminf(cm, __shfl_xor(cm, 2));
            cm = fminf(cm, __shfl_xor(cm, 4));
            cm = fminf(cm, __shfl_xor(cm, 8));
            if (ts == 0) d2acc += sqrtf(fmaxf(cm, FEPS));
        }
    }
    // row-min reduce across tk within wave (lanes l, l^16, l^32, l^48 share ts)
#pragma unroll
    for (int j = 0; j < 8; ++j) {
        rowmin[j] = fminf(rowmin[j], __shfl_xor(rowmin[j], 16));
        rowmin[j] = fminf(rowmin[j], __shfl_xor(rowmin[j], 32));
    }
    float* rowred = (float*)hist;   // reuse hist LDS: [4][128] floats
    if (l < 16) {                   // lane l<16 has ts == l
#pragma unroll
        for (int j = 0; j < 8; ++j) rowred[w * NS + l * 8 + j] = rowmin[j];
    }
    __syncthreads();
    float d1v = 0.0f;
    if (tid < NS) {
        float m = fminf(fminf(rowred[tid], rowred[NS + tid]),
                        fminf(rowred[2 * NS + tid], rowred[3 * NS + tid]));
        d1v = sqrtf(fmaxf(m, FEPS));
    }
    float t1 = block_sum_f(d1v, redf);
    float t2 = block_sum_f(d2acc, redf);
    if (tid == 0) {
        float cd2p = 0.5f * (t1 / ((float)NB * NS) + t2 / ((float)NB * NK));
        atomicAdd(out + 0, 1000.0f * cd2p);
        atomicAdd(out + 2, 1000.0f * cd2p);
        atomicAdd(out + 1, 1000.0f * 0.5f * cd1a / ((float)NB * NN));
    }
}

extern "C" void kernel_launch(void* const* d_in, const int* in_sizes, int n_in,
                              void* d_out, int out_size, void* d_ws, size_t ws_size,
                              hipStream_t stream) {
    const float* means = (const float*)d_in[0];
    const float* sp    = (const float*)d_in[1];
    const float* gt    = (const float*)d_in[2];
    float* out = (float*)d_out;

    hipMemsetAsync(d_out, 0, 3 * sizeof(float), stream);
    k_main<<<GROUP_BLOCKS + CD1B_BLOCKS, 256, 0, stream>>>(means, sp, gt, out);
}

// Round 9
// 149.774 us; speedup vs baseline: 1.2540x; 1.2540x over previous
//
#include <hip/hip_runtime.h>

#define NB 8
#define NN 256
#define NS 128
#define NM 8192
#define NK 200
#define KP1 201
#define FEPS 1e-9f
#define GROUP_BLOCKS (NB * NN)   // 2048
#define CD1B_BLOCKS 256
#define HBINS 2048

// ws layout (floats):
//  [0            .. 2*GB)   float2 per group block {t1, t2}   (cd2 partials)
//  [2*GB         .. 3*GB)   float per group block  cd1a       (cd1 term 1)
//  [3*GB         .. 3*GB+256) float per cd1b block t4         (cd1 term 2)

// ---------- reduction helpers (256 threads = 4 waves) ----------
__device__ __forceinline__ float block_sum_f(float v, float* redf) {
    const int tid = threadIdx.x, w = tid >> 6, l = tid & 63;
    for (int o = 32; o; o >>= 1) v += __shfl_xor(v, o);
    if (l == 0) redf[w] = v;
    __syncthreads();
    float t = redf[0] + redf[1] + redf[2] + redf[3];
    __syncthreads();
    return t;
}

// exclusive prefix over 256 threads; also returns block total
__device__ __forceinline__ int block_excl_scan_i(int v, int* redi, int tid, int& total) {
    const int l = tid & 63, w = tid >> 6;
    int x = v;
    for (int o = 1; o < 64; o <<= 1) { int y = __shfl_up(x, o); if (l >= o) x += y; }
    if (l == 63) redi[w] = x;
    __syncthreads();
    int woff = 0;
#pragma unroll
    for (int j = 0; j < 4; ++j) { if (j < w) woff += redi[j]; }
    total = redi[0] + redi[1] + redi[2] + redi[3];
    int ex = woff + x - v;
    __syncthreads();
    return ex;
}

// find the bin where the cumulative histogram count reaches rem;
// updates rem to the residual count needed inside that bin.
__device__ __forceinline__ int find_bin(int* hist, int nbins, int& rem,
                                        int* redi, int* ibc, int tid) {
    const int C = nbins >> 8;        // bins per thread (contiguous chunk)
    const int base = tid * C;
    int local = 0;
    for (int j = 0; j < C; ++j) local += hist[base + j];
    int total;
    int ex = block_excl_scan_i(local, redi, tid, total);
    if (ex < rem && rem <= ex + local) {       // exactly one thread
        int run = ex;
        for (int j = 0; j < C; ++j) {
            int h = hist[base + j];
            if (run + h >= rem) { ibc[0] = base + j; ibc[1] = rem - run; break; }
            run += h;
        }
    }
    __syncthreads();
    int bin = ibc[0]; rem = ibc[1];
    __syncthreads();
    return bin;
}

// ---------- main kernel: 2048 group blocks + 256 cd1b blocks ----------
// Per-block partials written with PLAIN stores (no global atomics).
__global__ __launch_bounds__(256)
void k_main(const float* __restrict__ means, const float* __restrict__ sp,
            const float* __restrict__ gt, float* __restrict__ ws) {
    __shared__ float gx[NK], gy[NK], gz[NK];
    __shared__ float sx[NS], sy[NS], sz[NS];
    __shared__ int   hist[HBINS];
    __shared__ float redf[4];
    __shared__ int   redi[4];
    __shared__ int   ibc[2];

    const int tid = threadIdx.x;
    const int w = tid >> 6, l = tid & 63;

    if (blockIdx.x >= GROUP_BLOCKS) {
        // ---- cd1 term 2: per (b,m) min over the 256 means ----
        const int blk = blockIdx.x - GROUP_BLOCKS;   // 0..255
        const int b = blk >> 5;
        const int m = ((blk & 31) << 8) + tid;
        float* mxs = (float*)hist;                   // reuse hist LDS (256*3 floats)
        float* mys = mxs + NN;
        float* mzs = mys + NN;
        const float* mb = means + (size_t)b * NN * 3;
        mxs[tid] = mb[tid * 3 + 0];
        mys[tid] = mb[tid * 3 + 1];
        mzs[tid] = mb[tid * 3 + 2];
        __syncthreads();
        const float* gp = gt + ((size_t)b * NM + m) * 3;
        const float px = gp[0], py = gp[1], pz = gp[2];
        float mn = 3.4e38f;
#pragma unroll 8
        for (int n = 0; n < NN; ++n) {
            float dx = px - mxs[n], dy = py - mys[n], dz = pz - mzs[n];
            mn = fminf(mn, fmaf(dx, dx, fmaf(dy, dy, dz * dz)));
        }
        float d2 = sqrtf(fmaxf(mn, FEPS));
        float t4 = block_sum_f(d2, redf);
        if (tid == 0) ws[3 * GROUP_BLOCKS + blk] = t4;
        return;
    }

    // ---- group path: one block per (b,n) ----
    const int bn = blockIdx.x;
    const int b  = bn >> 8;

    const float* spb = sp + (size_t)bn * NS * 3;
    if (tid < NS) {
        sx[tid] = spb[tid * 3 + 0];
        sy[tid] = spb[tid * 3 + 1];
        sz[tid] = spb[tid * 3 + 2];
    }
    const float mx = means[bn * 3 + 0];
    const float my = means[bn * 3 + 1];
    const float mz = means[bn * 3 + 2];
    const float* g = gt + (size_t)b * NM * 3;

    // 32 distances per thread in registers
    float vd[32];
    float vmin = 3.4e38f; int varg = -1;
#pragma unroll
    for (int i = 0; i < 32; ++i) {
        int m = tid + i * 256;
        float dx = mx - g[m * 3 + 0];
        float dy = my - g[m * 3 + 1];
        float dz = mz - g[m * 3 + 2];
        float d = fmaf(dx, dx, fmaf(dy, dy, dz * dz));
        vd[i] = d;
        if (d < vmin) { vmin = d; varg = m; }
    }

    // block argmin (value,index), lowest index on ties
    for (int o = 32; o; o >>= 1) {
        float ov = __shfl_xor(vmin, o);
        int   oi = __shfl_xor(varg, o);
        if (ov < vmin || (ov == vmin && oi < varg)) { vmin = ov; varg = oi; }
    }
    if (l == 0) { redf[w] = vmin; redi[w] = varg; }
    __syncthreads();
    float dmin = redf[0]; int m0 = redi[0];
#pragma unroll
    for (int i = 1; i < 4; ++i) {
        if (redf[i] < dmin || (redf[i] == dmin && redi[i] < m0)) { dmin = redf[i]; m0 = redi[i]; }
    }
    float cd1a = 0.0f;
    if (tid == 0) cd1a = sqrtf(fmaxf(dmin, FEPS));
    __syncthreads();

    // ---- exact 201st-smallest via 3-level histogram radix (bits 30..20, 19..9, 8..0) ----
    int rem = KP1;
    unsigned prefix;
    for (int j = tid; j < HBINS; j += 256) hist[j] = 0;
    __syncthreads();
#pragma unroll
    for (int i = 0; i < 32; ++i) atomicAdd(&hist[__float_as_uint(vd[i]) >> 20], 1);
    __syncthreads();
    prefix = (unsigned)find_bin(hist, 2048, rem, redi, ibc, tid);
    for (int j = tid; j < HBINS; j += 256) hist[j] = 0;
    __syncthreads();
#pragma unroll
    for (int i = 0; i < 32; ++i) {
        unsigned u = __float_as_uint(vd[i]);
        if ((u >> 20) == prefix) atomicAdd(&hist[(u >> 9) & 2047], 1);
    }
    __syncthreads();
    prefix = (prefix << 11) | (unsigned)find_bin(hist, 2048, rem, redi, ibc, tid);
    for (int j = tid; j < 512; j += 256) hist[j] = 0;
    __syncthreads();
#pragma unroll
    for (int i = 0; i < 32; ++i) {
        unsigned u = __float_as_uint(vd[i]);
        if ((u >> 9) == prefix) atomicAdd(&hist[u & 511], 1);
    }
    __syncthreads();
    const unsigned X = (prefix << 9) | (unsigned)find_bin(hist, 512, rem, redi, ibc, tid);

    // ---- gather selected set: strict-less via scan, ties fill ----
    int c = 0;
#pragma unroll
    for (int i = 0; i < 32; ++i) {
        int m = tid + i * 256;
        c += (m != m0 && __float_as_uint(vd[i]) < X);
    }
    int total;
    int p = block_excl_scan_i(c, redi, tid, total);
#pragma unroll
    for (int i = 0; i < 32; ++i) {
        int m = tid + i * 256;
        if (m != m0 && __float_as_uint(vd[i]) < X) {
            gx[p] = g[m * 3 + 0]; gy[p] = g[m * 3 + 1]; gz[p] = g[m * 3 + 2];
            ++p;
        }
    }
    if (tid == 0) ibc[0] = total;
    __syncthreads();
#pragma unroll
    for (int i = 0; i < 32; ++i) {
        int m = tid + i * 256;
        if (m != m0 && __float_as_uint(vd[i]) == X) {
            int q = atomicAdd(&ibc[0], 1);
            if (q < NK) { gx[q] = g[m * 3 + 0]; gy[q] = g[m * 3 + 1]; gz[q] = g[m * 3 + 2]; }
        }
    }
    __syncthreads();

    // ---- combined chamfer: one evaluation of the 128x200 matrix ----
    // thread (ts, tk) = (tid&15, tid>>4): 8 s-rows in regs x 13 k-cols.
    const int ts = tid & 15, tk = tid >> 4;
    float psx[8], psy[8], psz[8];
#pragma unroll
    for (int j = 0; j < 8; ++j) {
        int s = ts * 8 + j;
        psx[j] = sx[s]; psy[j] = sy[s]; psz[j] = sz[s];
    }
    float rowmin[8];
#pragma unroll
    for (int j = 0; j < 8; ++j) rowmin[j] = 3.4e38f;
    float d2acc = 0.0f;
#pragma unroll
    for (int i = 0; i < 13; ++i) {
        int k = tk + 16 * i;
        if (k < NK) {                       // wave-uniform: only waves 2,3 skip i==12
            float qx = gx[k], qy = gy[k], qz = gz[k];
            float cm = 3.4e38f;
#pragma unroll
            for (int j = 0; j < 8; ++j) {
                float dx = psx[j] - qx, dy = psy[j] - qy, dz = psz[j] - qz;
                float d = fmaf(dx, dx, fmaf(dy, dy, dz * dz));
                rowmin[j] = fminf(rowmin[j], d);
                cm = fminf(cm, d);
            }
            // col-min over the 16 lanes sharing tk (lanes are contiguous 16-groups)
            cm = fminf(cm, __shfl_xor(cm, 1));
            cm = fminf(cm, __shfl_xor(cm, 2));
            cm = fminf(cm, __shfl_xor(cm, 4));
            cm = fminf(cm, __shfl_xor(cm, 8));
            if (ts == 0) d2acc += sqrtf(fmaxf(cm, FEPS));
        }
    }
    // row-min reduce across tk within wave (lanes l, l^16, l^32, l^48 share ts)
#pragma unroll
    for (int j = 0; j < 8; ++j) {
        rowmin[j] = fminf(rowmin[j], __shfl_xor(rowmin[j], 16));
        rowmin[j] = fminf(rowmin[j], __shfl_xor(rowmin[j], 32));
    }
    float* rowred = (float*)hist;   // reuse hist LDS: [4][128] floats
    if (l < 16) {                   // lane l<16 has ts == l
#pragma unroll
        for (int j = 0; j < 8; ++j) rowred[w * NS + l * 8 + j] = rowmin[j];
    }
    __syncthreads();
    float d1v = 0.0f;
    if (tid < NS) {
        float m = fminf(fminf(rowred[tid], rowred[NS + tid]),
                        fminf(rowred[2 * NS + tid], rowred[3 * NS + tid]));
        d1v = sqrtf(fmaxf(m, FEPS));
    }
    float t1 = block_sum_f(d1v, redf);
    float t2 = block_sum_f(d2acc, redf);
    if (tid == 0) {
        float2* wsA = (float2*)ws;
        wsA[bn] = make_float2(t1, t2);
        ws[2 * GROUP_BLOCKS + bn] = cd1a;
    }
}

// ---------- featherweight finalize ----------
__global__ __launch_bounds__(256)
void k_fin(const float* __restrict__ ws, float* __restrict__ out) {
    __shared__ float red[4][4];
    const int tid = threadIdx.x, w = tid >> 6, l = tid & 63;
    float s1 = 0.0f, s2 = 0.0f, s3 = 0.0f, s4 = 0.0f;
    const float2* wsA = (const float2*)ws;
#pragma unroll
    for (int j = 0; j < GROUP_BLOCKS / 256; ++j) {
        float2 v = wsA[tid + j * 256];
        s1 += v.x; s2 += v.y;
        s3 += ws[2 * GROUP_BLOCKS + tid + j * 256];
    }
    s4 = ws[3 * GROUP_BLOCKS + tid];
    for (int o = 32; o; o >>= 1) {
        s1 += __shfl_xor(s1, o);
        s2 += __shfl_xor(s2, o);
        s3 += __shfl_xor(s3, o);
        s4 += __shfl_xor(s4, o);
    }
    if (l == 0) { red[w][0] = s1; red[w][1] = s2; red[w][2] = s3; red[w][3] = s4; }
    __syncthreads();
    if (tid == 0) {
        float t1 = 0.0f, t2 = 0.0f, t3 = 0.0f, t4 = 0.0f;
#pragma unroll
        for (int j = 0; j < 4; ++j) {
            t1 += red[j][0]; t2 += red[j][1]; t3 += red[j][2]; t4 += red[j][3];
        }
        float cd2 = 0.5f * (t1 / ((float)NB * NS) + t2 / ((float)NB * NK));
        float cd1 = 0.5f * (t3 / ((float)NB * NN) + t4 / ((float)NB * NM));
        out[0] = cd2 * 1000.0f;
        out[1] = cd1 * 1000.0f;
        out[2] = cd2 * 1000.0f;
    }
}

extern "C" void kernel_launch(void* const* d_in, const int* in_sizes, int n_in,
                              void* d_out, int out_size, void* d_ws, size_t ws_size,
                              hipStream_t stream) {
    const float* means = (const float*)d_in[0];
    const float* sp    = (const float*)d_in[1];
    const float* gt    = (const float*)d_in[2];
    float* out = (float*)d_out;
    float* ws  = (float*)d_ws;

    k_main<<<GROUP_BLOCKS + CD1B_BLOCKS, 256, 0, stream>>>(means, sp, gt, ws);
    k_fin<<<1, 256, 0, stream>>>(ws, out);
}

// Round 10
// 147.906 us; speedup vs baseline: 1.2698x; 1.0126x over previous
//
#include <hip/hip_runtime.h>

#define NB 8
#define NN 256
#define NS 128
#define NM 8192
#define NK 200
#define KP1 201
#define FEPS 1e-9f
#define GROUP_BLOCKS (NB * NN)   // 2048
#define CD1B_BLOCKS 256
#define HBINS 2048
#define GSTRIDE 608              // floats per grouped-set segment (3*200 padded)
#define GBASE 8192               // float offset of grouped data in ws

// ws layout (floats):
//  [0    .. 4096)  float2 per group block {t1, t2}   (cd2 partials)
//  [4096 .. 6144)  float per group block  cd1a       (cd1 term 1)
//  [6144 .. 6400)  float per cd1b block   t4         (cd1 term 2)
//  [8192 .. 8192+2048*608) grouped sets: per bn, [gx 200][gy 200][gz 200][pad 8]

// ---------- reduction helpers (256 threads = 4 waves) ----------
__device__ __forceinline__ float block_sum_f(float v, float* redf) {
    const int tid = threadIdx.x, w = tid >> 6, l = tid & 63;
    for (int o = 32; o; o >>= 1) v += __shfl_xor(v, o);
    if (l == 0) redf[w] = v;
    __syncthreads();
    float t = redf[0] + redf[1] + redf[2] + redf[3];
    __syncthreads();
    return t;
}

__device__ __forceinline__ int block_excl_scan_i(int v, int* redi, int tid, int& total) {
    const int l = tid & 63, w = tid >> 6;
    int x = v;
    for (int o = 1; o < 64; o <<= 1) { int y = __shfl_up(x, o); if (l >= o) x += y; }
    if (l == 63) redi[w] = x;
    __syncthreads();
    int woff = 0;
#pragma unroll
    for (int j = 0; j < 4; ++j) { if (j < w) woff += redi[j]; }
    total = redi[0] + redi[1] + redi[2] + redi[3];
    int ex = woff + x - v;
    __syncthreads();
    return ex;
}

__device__ __forceinline__ int find_bin(int* hist, int nbins, int& rem,
                                        int* redi, int* ibc, int tid) {
    const int C = nbins >> 8;
    const int base = tid * C;
    int local = 0;
    for (int j = 0; j < C; ++j) local += hist[base + j];
    int total;
    int ex = block_excl_scan_i(local, redi, tid, total);
    if (ex < rem && rem <= ex + local) {
        int run = ex;
        for (int j = 0; j < C; ++j) {
            int h = hist[base + j];
            if (run + h >= rem) { ibc[0] = base + j; ibc[1] = rem - run; break; }
            run += h;
        }
    }
    __syncthreads();
    int bin = ibc[0]; rem = ibc[1];
    __syncthreads();
    return bin;
}

// ---------- shared device body: distance + select + gather ----------
// Writes grouped set to gdst (global or LDS-backed float*), cd1a to ws.
__device__ __forceinline__ void select_body(const float* __restrict__ means,
                                            const float* __restrict__ gt,
                                            float* __restrict__ ws,
                                            float* __restrict__ gdst /*600+ floats*/) {
    __shared__ int   hist[HBINS];
    __shared__ float redf[4];
    __shared__ int   redi[4];
    __shared__ int   ibc[2];

    const int tid = threadIdx.x;
    const int w = tid >> 6, l = tid & 63;
    const int bn = blockIdx.x;
    const int b  = bn >> 8;

    const float mx = means[bn * 3 + 0];
    const float my = means[bn * 3 + 1];
    const float mz = means[bn * 3 + 2];
    const float* g = gt + (size_t)b * NM * 3;

    float vd[32];
    float vmin = 3.4e38f; int varg = -1;
#pragma unroll
    for (int i = 0; i < 32; ++i) {
        int m = tid + i * 256;
        float dx = mx - g[m * 3 + 0];
        float dy = my - g[m * 3 + 1];
        float dz = mz - g[m * 3 + 2];
        float d = fmaf(dx, dx, fmaf(dy, dy, dz * dz));
        vd[i] = d;
        if (d < vmin) { vmin = d; varg = m; }
    }

    for (int o = 32; o; o >>= 1) {
        float ov = __shfl_xor(vmin, o);
        int   oi = __shfl_xor(varg, o);
        if (ov < vmin || (ov == vmin && oi < varg)) { vmin = ov; varg = oi; }
    }
    if (l == 0) { redf[w] = vmin; redi[w] = varg; }
    __syncthreads();
    float dmin = redf[0]; int m0 = redi[0];
#pragma unroll
    for (int i = 1; i < 4; ++i) {
        if (redf[i] < dmin || (redf[i] == dmin && redi[i] < m0)) { dmin = redf[i]; m0 = redi[i]; }
    }
    if (tid == 0) ws[2 * GROUP_BLOCKS + bn] = sqrtf(fmaxf(dmin, FEPS));
    __syncthreads();

    // 3-level histogram radix select for the 201st smallest
    int rem = KP1;
    unsigned prefix;
    for (int j = tid; j < HBINS; j += 256) hist[j] = 0;
    __syncthreads();
#pragma unroll
    for (int i = 0; i < 32; ++i) atomicAdd(&hist[__float_as_uint(vd[i]) >> 20], 1);
    __syncthreads();
    prefix = (unsigned)find_bin(hist, 2048, rem, redi, ibc, tid);
    for (int j = tid; j < HBINS; j += 256) hist[j] = 0;
    __syncthreads();
#pragma unroll
    for (int i = 0; i < 32; ++i) {
        unsigned u = __float_as_uint(vd[i]);
        if ((u >> 20) == prefix) atomicAdd(&hist[(u >> 9) & 2047], 1);
    }
    __syncthreads();
    prefix = (prefix << 11) | (unsigned)find_bin(hist, 2048, rem, redi, ibc, tid);
    for (int j = tid; j < 512; j += 256) hist[j] = 0;
    __syncthreads();
#pragma unroll
    for (int i = 0; i < 32; ++i) {
        unsigned u = __float_as_uint(vd[i]);
        if ((u >> 9) == prefix) atomicAdd(&hist[u & 511], 1);
    }
    __syncthreads();
    const unsigned X = (prefix << 9) | (unsigned)find_bin(hist, 512, rem, redi, ibc, tid);

    // gather: strict-less via scan, ties fill
    int c = 0;
#pragma unroll
    for (int i = 0; i < 32; ++i) {
        int m = tid + i * 256;
        c += (m != m0 && __float_as_uint(vd[i]) < X);
    }
    int total;
    int p = block_excl_scan_i(c, redi, tid, total);
#pragma unroll
    for (int i = 0; i < 32; ++i) {
        int m = tid + i * 256;
        if (m != m0 && __float_as_uint(vd[i]) < X) {
            gdst[p]           = g[m * 3 + 0];
            gdst[NK + p]      = g[m * 3 + 1];
            gdst[2 * NK + p]  = g[m * 3 + 2];
            ++p;
        }
    }
    if (tid == 0) ibc[0] = total;
    __syncthreads();
#pragma unroll
    for (int i = 0; i < 32; ++i) {
        int m = tid + i * 256;
        if (m != m0 && __float_as_uint(vd[i]) == X) {
            int q = atomicAdd(&ibc[0], 1);
            if (q < NK) {
                gdst[q]           = g[m * 3 + 0];
                gdst[NK + q]      = g[m * 3 + 1];
                gdst[2 * NK + q]  = g[m * 3 + 2];
            }
        }
    }
}

// ---------- kernel A: select + gather to global ws ----------
__global__ __launch_bounds__(256)
void k_select(const float* __restrict__ means, const float* __restrict__ gt,
              float* __restrict__ ws) {
    select_body(means, gt, ws, ws + GBASE + (size_t)blockIdx.x * GSTRIDE);
}

// ---------- kernel B: chamfer (2048 group blocks) + cd1b (256 blocks) ----------
__global__ __launch_bounds__(256)
void k_chamfer(const float* __restrict__ means, const float* __restrict__ sp,
               const float* __restrict__ gt, float* __restrict__ ws) {
    __shared__ float pool[1496];
    __shared__ float redf[4];
    const int tid = threadIdx.x;
    const int w = tid >> 6, l = tid & 63;

    if (blockIdx.x >= GROUP_BLOCKS) {
        // cd1 term 2: per (b,m) min over the 256 means
        const int blk = blockIdx.x - GROUP_BLOCKS;
        const int b = blk >> 5;
        const int m = ((blk & 31) << 8) + tid;
        float* mxs = pool;         // 256
        float* mys = pool + 256;   // 256
        float* mzs = pool + 512;   // 256
        const float* mb = means + (size_t)b * NN * 3;
        mxs[tid] = mb[tid * 3 + 0];
        mys[tid] = mb[tid * 3 + 1];
        mzs[tid] = mb[tid * 3 + 2];
        __syncthreads();
        const float* gp = gt + ((size_t)b * NM + m) * 3;
        const float px = gp[0], py = gp[1], pz = gp[2];
        float mn = 3.4e38f;
#pragma unroll 8
        for (int n = 0; n < NN; ++n) {
            float dx = px - mxs[n], dy = py - mys[n], dz = pz - mzs[n];
            mn = fminf(mn, fmaf(dx, dx, fmaf(dy, dy, dz * dz)));
        }
        float d2 = sqrtf(fmaxf(mn, FEPS));
        float t4 = block_sum_f(d2, redf);
        if (tid == 0) ws[3 * GROUP_BLOCKS + blk] = t4;
        return;
    }

    const int bn = blockIdx.x;
    float* sx  = pool;          // 128
    float* sy  = pool + 128;
    float* sz  = pool + 256;
    float* gxs = pool + 384;    // 200
    float* gys = pool + 584;
    float* gzs = pool + 784;
    float* rowred = pool + 984; // 512

    const float* spb = sp + (size_t)bn * NS * 3;
    if (tid < NS) {
        sx[tid] = spb[tid * 3 + 0];
        sy[tid] = spb[tid * 3 + 1];
        sz[tid] = spb[tid * 3 + 2];
    }
    const float* gsrc = ws + GBASE + (size_t)bn * GSTRIDE;
    if (tid < NK) {
        gxs[tid] = gsrc[tid];
        gys[tid] = gsrc[NK + tid];
        gzs[tid] = gsrc[2 * NK + tid];
    }
    __syncthreads();

    // fused chamfer: thread (ts, tk) = (tid&15, tid>>4): 8 s-rows x 13 k-cols
    const int ts = tid & 15, tk = tid >> 4;
    float psx[8], psy[8], psz[8];
#pragma unroll
    for (int j = 0; j < 8; ++j) {
        int s = ts * 8 + j;
        psx[j] = sx[s]; psy[j] = sy[s]; psz[j] = sz[s];
    }
    float rowmin[8];
#pragma unroll
    for (int j = 0; j < 8; ++j) rowmin[j] = 3.4e38f;
    float d2acc = 0.0f;
#pragma unroll
    for (int i = 0; i < 13; ++i) {
        int k = tk + 16 * i;
        if (k < NK) {
            float qx = gxs[k], qy = gys[k], qz = gzs[k];
            float cm = 3.4e38f;
#pragma unroll
            for (int j = 0; j < 8; ++j) {
                float dx = psx[j] - qx, dy = psy[j] - qy, dz = psz[j] - qz;
                float d = fmaf(dx, dx, fmaf(dy, dy, dz * dz));
                rowmin[j] = fminf(rowmin[j], d);
                cm = fminf(cm, d);
            }
            cm = fminf(cm, __shfl_xor(cm, 1));
            cm = fminf(cm, __shfl_xor(cm, 2));
            cm = fminf(cm, __shfl_xor(cm, 4));
            cm = fminf(cm, __shfl_xor(cm, 8));
            if (ts == 0) d2acc += sqrtf(fmaxf(cm, FEPS));
        }
    }
#pragma unroll
    for (int j = 0; j < 8; ++j) {
        rowmin[j] = fminf(rowmin[j], __shfl_xor(rowmin[j], 16));
        rowmin[j] = fminf(rowmin[j], __shfl_xor(rowmin[j], 32));
    }
    if (l < 16) {
#pragma unroll
        for (int j = 0; j < 8; ++j) rowred[w * NS + l * 8 + j] = rowmin[j];
    }
    __syncthreads();
    float d1v = 0.0f;
    if (tid < NS) {
        float m = fminf(fminf(rowred[tid], rowred[NS + tid]),
                        fminf(rowred[2 * NS + tid], rowred[3 * NS + tid]));
        d1v = sqrtf(fmaxf(m, FEPS));
    }
    float t1 = block_sum_f(d1v, redf);
    float t2 = block_sum_f(d2acc, redf);
    if (tid == 0) {
        float2* wsA = (float2*)ws;
        wsA[bn] = make_float2(t1, t2);
    }
}

// ---------- monolithic fallback (R9 k_main) for small ws ----------
__global__ __launch_bounds__(256)
void k_main(const float* __restrict__ means, const float* __restrict__ sp,
            const float* __restrict__ gt, float* __restrict__ ws) {
    __shared__ float gx[NK], gy[NK], gz[NK];
    __shared__ float sx[NS], sy[NS], sz[NS];
    __shared__ float redf2[4];

    const int tid = threadIdx.x;
    const int w = tid >> 6, l = tid & 63;

    if (blockIdx.x >= GROUP_BLOCKS) {
        const int blk = blockIdx.x - GROUP_BLOCKS;
        const int b = blk >> 5;
        const int m = ((blk & 31) << 8) + tid;
        __shared__ float mpool[768];
        float* mxs = mpool;
        float* mys = mpool + 256;
        float* mzs = mpool + 512;
        const float* mb = means + (size_t)b * NN * 3;
        mxs[tid] = mb[tid * 3 + 0];
        mys[tid] = mb[tid * 3 + 1];
        mzs[tid] = mb[tid * 3 + 2];
        __syncthreads();
        const float* gp = gt + ((size_t)b * NM + m) * 3;
        const float px = gp[0], py = gp[1], pz = gp[2];
        float mn = 3.4e38f;
#pragma unroll 8
        for (int n = 0; n < NN; ++n) {
            float dx = px - mxs[n], dy = py - mys[n], dz = pz - mzs[n];
            mn = fminf(mn, fmaf(dx, dx, fmaf(dy, dy, dz * dz)));
        }
        float d2 = sqrtf(fmaxf(mn, FEPS));
        float t4 = block_sum_f(d2, redf2);
        if (tid == 0) ws[3 * GROUP_BLOCKS + blk] = t4;
        return;
    }

    const int bn = blockIdx.x;
    const float* spb = sp + (size_t)bn * NS * 3;
    if (tid < NS) {
        sx[tid] = spb[tid * 3 + 0];
        sy[tid] = spb[tid * 3 + 1];
        sz[tid] = spb[tid * 3 + 2];
    }
    // select + gather into LDS (gx/gy/gz are contiguous: gx base ptr works)
    select_body(means, gt, ws, gx);
    __syncthreads();

    const int ts = tid & 15, tk = tid >> 4;
    float psx[8], psy[8], psz[8];
#pragma unroll
    for (int j = 0; j < 8; ++j) {
        int s = ts * 8 + j;
        psx[j] = sx[s]; psy[j] = sy[s]; psz[j] = sz[s];
    }
    float rowmin[8];
#pragma unroll
    for (int j = 0; j < 8; ++j) rowmin[j] = 3.4e38f;
    float d2acc = 0.0f;
#pragma unroll
    for (int i = 0; i < 13; ++i) {
        int k = tk + 16 * i;
        if (k < NK) {
            float qx = gx[k], qy = gy[k], qz = gz[k];
            float cm = 3.4e38f;
#pragma unroll
            for (int j = 0; j < 8; ++j) {
                float dx = psx[j] - qx, dy = psy[j] - qy, dz = psz[j] - qz;
                float d = fmaf(dx, dx, fmaf(dy, dy, dz * dz));
                rowmin[j] = fminf(rowmin[j], d);
                cm = fminf(cm, d);
            }
            cm = fminf(cm, __shfl_xor(cm, 1));
            cm = fminf(cm, __shfl_xor(cm, 2));
            cm = fminf(cm, __shfl_xor(cm, 4));
            cm = fminf(cm, __shfl_xor(cm, 8));
            if (ts == 0) d2acc += sqrtf(fmaxf(cm, FEPS));
        }
    }
#pragma unroll
    for (int j = 0; j < 8; ++j) {
        rowmin[j] = fminf(rowmin[j], __shfl_xor(rowmin[j], 16));
        rowmin[j] = fminf(rowmin[j], __shfl_xor(rowmin[j], 32));
    }
    __shared__ float rowred[512];
    if (l < 16) {
#pragma unroll
        for (int j = 0; j < 8; ++j) rowred[w * NS + l * 8 + j] = rowmin[j];
    }
    __syncthreads();
    float d1v = 0.0f;
    if (tid < NS) {
        float m = fminf(fminf(rowred[tid], rowred[NS + tid]),
                        fminf(rowred[2 * NS + tid], rowred[3 * NS + tid]));
        d1v = sqrtf(fmaxf(m, FEPS));
    }
    float t1 = block_sum_f(d1v, redf2);
    float t2 = block_sum_f(d2acc, redf2);
    if (tid == 0) {
        float2* wsA = (float2*)ws;
        wsA[bn] = make_float2(t1, t2);
    }
}

// ---------- featherweight finalize ----------
__global__ __launch_bounds__(256)
void k_fin(const float* __restrict__ ws, float* __restrict__ out) {
    __shared__ float red[4][4];
    const int tid = threadIdx.x, w = tid >> 6, l = tid & 63;
    float s1 = 0.0f, s2 = 0.0f, s3 = 0.0f, s4 = 0.0f;
    const float2* wsA = (const float2*)ws;
#pragma unroll
    for (int j = 0; j < GROUP_BLOCKS / 256; ++j) {
        float2 v = wsA[tid + j * 256];
        s1 += v.x; s2 += v.y;
        s3 += ws[2 * GROUP_BLOCKS + tid + j * 256];
    }
    s4 = ws[3 * GROUP_BLOCKS + tid];
    for (int o = 32; o; o >>= 1) {
        s1 += __shfl_xor(s1, o);
        s2 += __shfl_xor(s2, o);
        s3 += __shfl_xor(s3, o);
        s4 += __shfl_xor(s4, o);
    }
    if (l == 0) { red[w][0] = s1; red[w][1] = s2; red[w][2] = s3; red[w][3] = s4; }
    __syncthreads();
    if (tid == 0) {
        float t1 = 0.0f, t2 = 0.0f, t3 = 0.0f, t4 = 0.0f;
#pragma unroll
        for (int j = 0; j < 4; ++j) {
            t1 += red[j][0]; t2 += red[j][1]; t3 += red[j][2]; t4 += red[j][3];
        }
        float cd2 = 0.5f * (t1 / ((float)NB * NS) + t2 / ((float)NB * NK));
        float cd1 = 0.5f * (t3 / ((float)NB * NN) + t4 / ((float)NB * NM));
        out[0] = cd2 * 1000.0f;
        out[1] = cd1 * 1000.0f;
        out[2] = cd2 * 1000.0f;
    }
}

extern "C" void kernel_launch(void* const* d_in, const int* in_sizes, int n_in,
                              void* d_out, int out_size, void* d_ws, size_t ws_size,
                              hipStream_t stream) {
    const float* means = (const float*)d_in[0];
    const float* sp    = (const float*)d_in[1];
    const float* gt    = (const float*)d_in[2];
    float* out = (float*)d_out;
    float* ws  = (float*)d_ws;

    const size_t need = (size_t)(GBASE + GROUP_BLOCKS * GSTRIDE) * sizeof(float);
    if (ws_size >= need) {
        k_select<<<GROUP_BLOCKS, 256, 0, stream>>>(means, gt, ws);
        k_chamfer<<<GROUP_BLOCKS + CD1B_BLOCKS, 256, 0, stream>>>(means, sp, gt, ws);
        k_fin<<<1, 256, 0, stream>>>(ws, out);
    } else {
        k_main<<<GROUP_BLOCKS + CD1B_BLOCKS, 256, 0, stream>>>(means, sp, gt, ws);
        k_fin<<<1, 256, 0, stream>>>(ws, out);
    }
}

// Round 13
// 138.062 us; speedup vs baseline: 1.3603x; 1.0713x over previous
//
#include <hip/hip_runtime.h>

#define NB 8
#define NN 256
#define NS 128
#define NM 8192
#define NK 200
#define KP1 201
#define FEPS 1e-9f
#define GROUP_BLOCKS (NB * NN)   // 2048
#define CD1B_BLOCKS 256
#define HBINS 2048

// ws layout (floats):
//  [0    .. 4096)  float2 per group block {t1, t2}   (cd2 partials)
//  [4096 .. 6144)  float per group block  cd1a       (cd1 term 1)
//  [6144 .. 6400)  float per cd1b block   t4         (cd1 term 2)

// ---------- reduction helpers (256 threads = 4 waves) ----------
__device__ __forceinline__ float block_sum_f(float v, float* redf) {
    const int tid = threadIdx.x, w = tid >> 6, l = tid & 63;
    for (int o = 32; o; o >>= 1) v += __shfl_xor(v, o);
    if (l == 0) redf[w] = v;
    __syncthreads();
    float t = redf[0] + redf[1] + redf[2] + redf[3];
    __syncthreads();
    return t;
}

__device__ __forceinline__ int block_excl_scan_i(int v, int* redi, int tid, int& total) {
    const int l = tid & 63, w = tid >> 6;
    int x = v;
    for (int o = 1; o < 64; o <<= 1) { int y = __shfl_up(x, o); if (l >= o) x += y; }
    if (l == 63) redi[w] = x;
    __syncthreads();
    int woff = 0;
#pragma unroll
    for (int j = 0; j < 4; ++j) { if (j < w) woff += redi[j]; }
    total = redi[0] + redi[1] + redi[2] + redi[3];
    int ex = woff + x - v;
    __syncthreads();
    return ex;
}

__device__ __forceinline__ int find_bin(int* hist, int nbins, int& rem,
                                        int* redi, int* ibc, int tid) {
    const int C = nbins >> 8;
    const int base = tid * C;
    int local = 0;
    for (int j = 0; j < C; ++j) local += hist[base + j];
    int total;
    int ex = block_excl_scan_i(local, redi, tid, total);
    if (ex < rem && rem <= ex + local) {
        int run = ex;
        for (int j = 0; j < C; ++j) {
            int h = hist[base + j];
            if (run + h >= rem) { ibc[0] = base + j; ibc[1] = rem - run; break; }
            run += h;
        }
    }
    __syncthreads();
    int bin = ibc[0]; rem = ibc[1];
    __syncthreads();
    return bin;
}

// ---------- fused kernel: 2048 group blocks + 256 cd1b blocks ----------
__global__ __launch_bounds__(256)
void k_main(const float* __restrict__ means, const float* __restrict__ sp,
            const float* __restrict__ gt, float* __restrict__ ws) {
    __shared__ int   hist[HBINS];                 // 8KB; reused: cd1b mpool, rowred
    __shared__ float gx[NK], gy[NK], gz[NK], g2s[NK];
    __shared__ float sx[NS], sy[NS], sz[NS];
    __shared__ float redf[4];
    __shared__ int   redi[4];
    __shared__ int   ibc[2];

    const int tid = threadIdx.x;
    const int w = tid >> 6, l = tid & 63;

    if (blockIdx.x >= GROUP_BLOCKS) {
        // ---- cd1 term 2: per (b,m) min over the 256 means ----
        const int blk = blockIdx.x - GROUP_BLOCKS;
        const int b = blk >> 5;
        const int m = ((blk & 31) << 8) + tid;
        float* mxs = (float*)hist;                // 768 floats in 8KB pool
        float* mys = mxs + NN;
        float* mzs = mys + NN;
        const float* mb = means + (size_t)b * NN * 3;
        mxs[tid] = mb[tid * 3 + 0];
        mys[tid] = mb[tid * 3 + 1];
        mzs[tid] = mb[tid * 3 + 2];
        __syncthreads();
        const float* gp = gt + ((size_t)b * NM + m) * 3;
        const float px = gp[0], py = gp[1], pz = gp[2];
        float mn = 3.4e38f;
#pragma unroll 8
        for (int n = 0; n < NN; ++n) {
            float dx = px - mxs[n], dy = py - mys[n], dz = pz - mzs[n];
            mn = fminf(mn, fmaf(dx, dx, fmaf(dy, dy, dz * dz)));
        }
        float d2 = sqrtf(fmaxf(mn, FEPS));
        float t4 = block_sum_f(d2, redf);
        if (tid == 0) ws[3 * GROUP_BLOCKS + blk] = t4;
        return;
    }

    // ---- group path: one block per (b,n) ----
    const int bn = blockIdx.x;
    const int b  = bn >> 8;

    const float* spb = sp + (size_t)bn * NS * 3;
    if (tid < NS) {
        sx[tid] = spb[tid * 3 + 0];
        sy[tid] = spb[tid * 3 + 1];
        sz[tid] = spb[tid * 3 + 2];
    }
    const float mx = means[bn * 3 + 0];
    const float my = means[bn * 3 + 1];
    const float mz = means[bn * 3 + 2];
    const float* g = gt + (size_t)b * NM * 3;

    // ---- distances: contiguous float4 loads; thread owns m in [tid*32, tid*32+32) ----
    const float* gtb = g + tid * 96;              // 96 floats = 32 points, 16B-aligned
    float vd[32];
    float vmin = 3.4e38f; int varg = -1;
#pragma unroll
    for (int c = 0; c < 8; ++c) {
        float4 f0 = *(const float4*)(gtb + c * 12);
        float4 f1 = *(const float4*)(gtb + c * 12 + 4);
        float4 f2 = *(const float4*)(gtb + c * 12 + 8);
        float px[4] = {f0.x, f0.w, f1.z, f2.y};
        float py[4] = {f0.y, f1.x, f1.w, f2.z};
        float pz[4] = {f0.z, f1.y, f2.x, f2.w};
#pragma unroll
        for (int j = 0; j < 4; ++j) {
            int i = c * 4 + j;
            float dx = mx - px[j], dy = my - py[j], dz = mz - pz[j];
            float d = fmaf(dx, dx, fmaf(dy, dy, dz * dz));
            vd[i] = d;
            if (d < vmin) { vmin = d; varg = tid * 32 + i; }  // first (lowest m) kept on ties
        }
    }

    // block argmin (value,index), lowest index on ties
    for (int o = 32; o; o >>= 1) {
        float ov = __shfl_xor(vmin, o);
        int   oi = __shfl_xor(varg, o);
        if (ov < vmin || (ov == vmin && oi < varg)) { vmin = ov; varg = oi; }
    }
    if (l == 0) { redf[w] = vmin; redi[w] = varg; }
    __syncthreads();
    float dmin = redf[0]; int m0 = redi[0];
#pragma unroll
    for (int i = 1; i < 4; ++i) {
        if (redf[i] < dmin || (redf[i] == dmin && redi[i] < m0)) { dmin = redf[i]; m0 = redi[i]; }
    }
    if (tid == 0) ws[2 * GROUP_BLOCKS + bn] = sqrtf(fmaxf(dmin, FEPS));
    __syncthreads();

    // ---- exact 201st-smallest via 3-level histogram radix ----
    int rem = KP1;
    unsigned prefix;
    for (int j = tid; j < HBINS; j += 256) hist[j] = 0;
    __syncthreads();
#pragma unroll
    for (int i = 0; i < 32; ++i) atomicAdd(&hist[__float_as_uint(vd[i]) >> 20], 1);
    __syncthreads();
    prefix = (unsigned)find_bin(hist, 2048, rem, redi, ibc, tid);
    for (int j = tid; j < HBINS; j += 256) hist[j] = 0;
    __syncthreads();
#pragma unroll
    for (int i = 0; i < 32; ++i) {
        unsigned u = __float_as_uint(vd[i]);
        if ((u >> 20) == prefix) atomicAdd(&hist[(u >> 9) & 2047], 1);
    }
    __syncthreads();
    prefix = (prefix << 11) | (unsigned)find_bin(hist, 2048, rem, redi, ibc, tid);
    for (int j = tid; j < 512; j += 256) hist[j] = 0;
    __syncthreads();
#pragma unroll
    for (int i = 0; i < 32; ++i) {
        unsigned u = __float_as_uint(vd[i]);
        if ((u >> 9) == prefix) atomicAdd(&hist[u & 511], 1);
    }
    __syncthreads();
    const unsigned X = (prefix << 9) | (unsigned)find_bin(hist, 512, rem, redi, ibc, tid);

    // ---- gather: strict-less via scan, ties fill; also |g|^2 into LDS ----
    int c = 0;
#pragma unroll
    for (int i = 0; i < 32; ++i) {
        int m = tid * 32 + i;
        c += (m != m0 && __float_as_uint(vd[i]) < X);
    }
    int total;
    int p = block_excl_scan_i(c, redi, tid, total);
#pragma unroll
    for (int i = 0; i < 32; ++i) {
        int m = tid * 32 + i;
        if (m != m0 && __float_as_uint(vd[i]) < X) {
            float x = g[m * 3 + 0], y = g[m * 3 + 1], z = g[m * 3 + 2];
            gx[p] = x; gy[p] = y; gz[p] = z;
            g2s[p] = fmaf(x, x, fmaf(y, y, z * z));
            ++p;
        }
    }
    if (tid == 0) ibc[0] = total;
    __syncthreads();
#pragma unroll
    for (int i = 0; i < 32; ++i) {
        int m = tid * 32 + i;
        if (m != m0 && __float_as_uint(vd[i]) == X) {
            int q = atomicAdd(&ibc[0], 1);
            if (q < NK) {
                float x = g[m * 3 + 0], y = g[m * 3 + 1], z = g[m * 3 + 2];
                gx[q] = x; gy[q] = y; gz[q] = z;
                g2s[q] = fmaf(x, x, fmaf(y, y, z * z));
            }
        }
    }
    __syncthreads();

    // ---- fused chamfer via d = |s|^2 + |g|^2 - 2 s.g (matches reference algebra) ----
    // thread (ts, tk) = (tid&15, tid>>4): 8 s-rows in regs x k-cols.
    const int ts = tid & 15, tk = tid >> 4;
    float psx[8], psy[8], psz[8], s2[8];
#pragma unroll
    for (int j = 0; j < 8; ++j) {
        int s = ts * 8 + j;
        float x = sx[s], y = sy[s], z = sz[s];
        s2[j] = fmaf(x, x, fmaf(y, y, z * z));
        psx[j] = -2.0f * x; psy[j] = -2.0f * y; psz[j] = -2.0f * z;  // fold -2 into s
    }
    float rowacc[8];
#pragma unroll
    for (int j = 0; j < 8; ++j) rowacc[j] = 3.4e38f;
    float d2acc = 0.0f;
    // 6 uniform pairs of k-columns (covers k-iters 0..11)
#pragma unroll
    for (int ip = 0; ip < 6; ++ip) {
        int k0 = tk + 32 * ip, k1 = k0 + 16;
        float qx0 = gx[k0], qy0 = gy[k0], qz0 = gz[k0], hg0 = g2s[k0];
        float qx1 = gx[k1], qy1 = gy[k1], qz1 = gz[k1], hg1 = g2s[k1];
        float cm0 = 3.4e38f, cm1 = 3.4e38f;
#pragma unroll
        for (int j = 0; j < 8; ++j) {
            float f0 = fmaf(psx[j], qx0, fmaf(psy[j], qy0, psz[j] * qz0));  // -2 s.g
            float f1 = fmaf(psx[j], qx1, fmaf(psy[j], qy1, psz[j] * qz1));
            rowacc[j] = fminf(fminf(rowacc[j], hg0 + f0), hg1 + f1);        // min3 fusion
            cm0 = fminf(cm0, s2[j] + f0);
            cm1 = fminf(cm1, s2[j] + f1);
        }
        cm0 = fminf(cm0, __shfl_xor(cm0, 1));
        cm0 = fminf(cm0, __shfl_xor(cm0, 2));
        cm0 = fminf(cm0, __shfl_xor(cm0, 4));
        cm0 = fminf(cm0, __shfl_xor(cm0, 8));
        cm1 = fminf(cm1, __shfl_xor(cm1, 1));
        cm1 = fminf(cm1, __shfl_xor(cm1, 2));
        cm1 = fminf(cm1, __shfl_xor(cm1, 4));
        cm1 = fminf(cm1, __shfl_xor(cm1, 8));
        if (ts == 0)
            d2acc += sqrtf(fmaxf(hg0 + cm0, FEPS)) + sqrtf(fmaxf(hg1 + cm1, FEPS));
    }
    // leftover column k = 192 + tk (valid for tk < 8; wave-uniform)
    if (tk < 8) {
        int k = 192 + tk;
        float qx0 = gx[k], qy0 = gy[k], qz0 = gz[k], hg0 = g2s[k];
        float cm0 = 3.4e38f;
#pragma unroll
        for (int j = 0; j < 8; ++j) {
            float f0 = fmaf(psx[j], qx0, fmaf(psy[j], qy0, psz[j] * qz0));
            rowacc[j] = fminf(rowacc[j], hg0 + f0);
            cm0 = fminf(cm0, s2[j] + f0);
        }
        cm0 = fminf(cm0, __shfl_xor(cm0, 1));
        cm0 = fminf(cm0, __shfl_xor(cm0, 2));
        cm0 = fminf(cm0, __shfl_xor(cm0, 4));
        cm0 = fminf(cm0, __shfl_xor(cm0, 8));
        if (ts == 0) d2acc += sqrtf(fmaxf(hg0 + cm0, FEPS));
    }
    // row-min reduce across tk within wave; add |s|^2 before staging
#pragma unroll
    for (int j = 0; j < 8; ++j) {
        rowacc[j] = fminf(rowacc[j], __shfl_xor(rowacc[j], 16));
        rowacc[j] = fminf(rowacc[j], __shfl_xor(rowacc[j], 32));
        rowacc[j] += s2[j];
    }
    float* rowred = (float*)hist;   // reuse hist LDS: [4][128] floats
    if (l < 16) {
#pragma unroll
        for (int j = 0; j < 8; ++j) rowred[w * NS + l * 8 + j] = rowacc[j];
    }
    __syncthreads();
    float d1v = 0.0f;
    if (tid < NS) {
        float m = fminf(fminf(rowred[tid], rowred[NS + tid]),
                        fminf(rowred[2 * NS + tid], rowred[3 * NS + tid]));
        d1v = sqrtf(fmaxf(m, FEPS));
    }
    float t1 = block_sum_f(d1v, redf);
    float t2 = block_sum_f(d2acc, redf);
    if (tid == 0) {
        float2* wsA = (float2*)ws;
        wsA[bn] = make_float2(t1, t2);
    }
}

// ---------- featherweight finalize ----------
__global__ __launch_bounds__(256)
void k_fin(const float* __restrict__ ws, float* __restrict__ out) {
    __shared__ float red[4][4];
    const int tid = threadIdx.x, w = tid >> 6, l = tid & 63;
    float s1 = 0.0f, s2 = 0.0f, s3 = 0.0f, s4 = 0.0f;
    const float2* wsA = (const float2*)ws;
#pragma unroll
    for (int j = 0; j < GROUP_BLOCKS / 256; ++j) {
        float2 v = wsA[tid + j * 256];
        s1 += v.x; s2 += v.y;
        s3 += ws[2 * GROUP_BLOCKS + tid + j * 256];
    }
    s4 = ws[3 * GROUP_BLOCKS + tid];
    for (int o = 32; o; o >>= 1) {
        s1 += __shfl_xor(s1, o);
        s2 += __shfl_xor(s2, o);
        s3 += __shfl_xor(s3, o);
        s4 += __shfl_xor(s4, o);
    }
    if (l == 0) { red[w][0] = s1; red[w][1] = s2; red[w][2] = s3; red[w][3] = s4; }
    __syncthreads();
    if (tid == 0) {
        float t1 = 0.0f, t2 = 0.0f, t3 = 0.0f, t4 = 0.0f;
#pragma unroll
        for (int j = 0; j < 4; ++j) {
            t1 += red[j][0]; t2 += red[j][1]; t3 += red[j][2]; t4 += red[j][3];
        }
        float cd2 = 0.5f * (t1 / ((float)NB * NS) + t2 / ((float)NB * NK));
        float cd1 = 0.5f * (t3 / ((float)NB * NN) + t4 / ((float)NB * NM));
        out[0] = cd2 * 1000.0f;
        out[1] = cd1 * 1000.0f;
        out[2] = cd2 * 1000.0f;
    }
}

extern "C" void kernel_launch(void* const* d_in, const int* in_sizes, int n_in,
                              void* d_out, int out_size, void* d_ws, size_t ws_size,
                              hipStream_t stream) {
    const float* means = (const float*)d_in[0];
    const float* sp    = (const float*)d_in[1];
    const float* gt    = (const float*)d_in[2];
    float* out = (float*)d_out;
    float* ws  = (float*)d_ws;

    k_main<<<GROUP_BLOCKS + CD1B_BLOCKS, 256, 0, stream>>>(means, sp, gt, ws);
    k_fin<<<1, 256, 0, stream>>>(ws, out);
}